// Round 7
// baseline (220.264 us; speedup 1.0000x reference)
//
#include <hip/hip_runtime.h>
#include <hip/hip_bf16.h>

typedef __attribute__((ext_vector_type(4))) float  f32x4;
typedef __attribute__((ext_vector_type(8))) short  s16x8;
typedef __attribute__((ext_vector_type(4))) short  s16x4;

#define NB_    16
#define NH_    128
#define NS_    4096
#define ND_    512
#define NDPE_  64
#define NDT_   576
#define NCHUNK 16
#define CHUNK_ 256
#define TS_    32
#define NSUB_  8
#define NT_    256           // 4 waves; each wave: 16 heads, full 512-d (R1 workload)

#define KROW_S 580           // kbuf row: 576 + 4 pad shorts (290 dw; b128 reads bank-optimal)
#define VT_ROW 36            // vbufT row: 32 + 4 pad shorts (72 B rows -> 8B-aligned b64 reads)
#define PROW   40            // pbuf row (aliased onto kbuf region)

#define KBUF_BYTES (TS_ * KROW_S * 2)        // 37120
#define VBUF_OFF   KBUF_BYTES
#define VBUF_BYTES (ND_ * VT_ROW * 2)        // 36864
#define SMEM_BYTES (KBUF_BYTES + VBUF_BYTES) // 73984  (x2 blocks = 147968 <= 163840)

// (1/sqrt(576)) * log2(e)
#define CL2 0.06011229337037348f

__device__ __forceinline__ unsigned pk_bf16(float a, float b) {
    union { __hip_bfloat162 h2; unsigned u; } c;
    c.h2 = __float22bfloat162_rn(make_float2(a, b));
    return c.u;
}
__device__ __forceinline__ unsigned short bf1(float a) {
    union { __hip_bfloat16 h; unsigned short u; } c;
    c.h = __float2bfloat16(a);
    return c.u;
}

__global__ void qcvt(const float* __restrict__ q, const float* __restrict__ q_pe,
                     unsigned short* __restrict__ qbf) {
    const int idx = blockIdx.x * 256 + threadIdx.x;   // pair index
    if (idx >= NB_ * NH_ * (NDT_ / 2)) return;
    const int bh = idx / (NDT_ / 2), pc = idx - bh * (NDT_ / 2);
    const int c = pc * 2;
    const float* src = (c < ND_) ? (q + (size_t)bh * ND_ + c)
                                 : (q_pe + (size_t)bh * NDPE_ + (c - ND_));
    *(unsigned*)&qbf[(size_t)bh * NDT_ + c] = pk_bf16(src[0], src[1]);
}

__global__ __launch_bounds__(NT_, 2) void mla_attn(
    const float* __restrict__ k, const float* __restrict__ k_pe,
    const unsigned short* __restrict__ qbf,
    unsigned short* __restrict__ opart, float* __restrict__ mlbuf)
{
    extern __shared__ char smem[];
    unsigned short* kbuf = (unsigned short*)(smem);              // [32][580] bf16
    unsigned short* vbuf = (unsigned short*)(smem + VBUF_OFF);   // [512][36] bf16 (V^T)
    unsigned short* pbuf = (unsigned short*)(smem);              // ALIAS on kbuf: 4 x [16][40]

    // grid: 512 blocks. Pair (16m+v, 16m+v+8) shares (chunk,b) and (round-robin)
    // lands on the same XCD -> second block's K reads are L2 hits.
    const int bid  = blockIdx.x;
    const int hgrp = (bid >> 3) & 1;
    const int u    = (bid & 7) | ((bid >> 4) << 3);   // 0..255
    const int chunk = u & 15, b = u >> 4;

    const int tid = threadIdx.x;
    const int wv  = tid >> 6;
    const int l   = tid & 63;
    const int l16 = l & 15;
    const int lq  = l >> 4;

    f32x4 acc[32];
    #pragma unroll
    for (int i = 0; i < 32; ++i) acc[i] = (f32x4)0.0f;
    float m2[4]   = {-1e30f, -1e30f, -1e30f, -1e30f};
    float lsum[4] = {0.f, 0.f, 0.f, 0.f};

    const unsigned short* qrowb =
        qbf + (size_t)(b * NH_ + hgrp * 64 + wv * 16 + l16) * NDT_ + lq * 8;
    unsigned short* prow = pbuf + wv * 16 * PROW;

    for (int t = 0; t < NSUB_; ++t) {
        // ---------------- stage tile: f32 -> bf16 kbuf + V^T scatter ----------------
        {
            const int sbase = b * NS_ + chunk * CHUNK_ + t * TS_;
            #pragma unroll
            for (int j = 0; j < 16; ++j) {            // k part: 4096 granules / 256 thr
                const int g = tid + NT_ * j;
                const int s = g >> 7;
                const int d = (g & 127) * 4;
                const f32x4 v = *(const f32x4*)(k + (size_t)(sbase + s) * ND_ + d);
                const unsigned lo = pk_bf16(v.x, v.y), hi = pk_bf16(v.z, v.w);
                *(unsigned long long*)&kbuf[s * KROW_S + d] =
                    (unsigned long long)lo | ((unsigned long long)hi << 32);
                vbuf[(d + 0) * VT_ROW + s] = (unsigned short)(lo);
                vbuf[(d + 1) * VT_ROW + s] = (unsigned short)(lo >> 16);
                vbuf[(d + 2) * VT_ROW + s] = (unsigned short)(hi);
                vbuf[(d + 3) * VT_ROW + s] = (unsigned short)(hi >> 16);
            }
            #pragma unroll
            for (int j = 0; j < 2; ++j) {             // pe part: 512 granules
                const int g = tid + NT_ * j;
                const int s = g >> 4;
                const int dp = (g & 15) * 4;
                const f32x4 v = *(const f32x4*)(k_pe + (size_t)(sbase + s) * NDPE_ + dp);
                const unsigned lo = pk_bf16(v.x, v.y), hi = pk_bf16(v.z, v.w);
                *(unsigned long long*)&kbuf[s * KROW_S + ND_ + dp] =
                    (unsigned long long)lo | ((unsigned long long)hi << 32);
            }
        }
        __syncthreads();

        // ---------------- QK^T : scores[16h x 32s] per wave, full 576 dims ----------------
        f32x4 sc0 = (f32x4)0.0f, sc1 = (f32x4)0.0f;
        #pragma unroll
        for (int i = 0; i < 18; ++i) {
            const int d0 = i * 32 + lq * 8;
            const s16x8 af = *(const s16x8*)(qrowb + i * 32);
            const s16x8 b0 = *(const s16x8*)&kbuf[(l16     ) * KROW_S + d0];
            const s16x8 b1 = *(const s16x8*)&kbuf[(l16 + 16) * KROW_S + d0];
            sc0 = __builtin_amdgcn_mfma_f32_16x16x32_bf16(af, b0, sc0, 0, 0, 0);
            sc1 = __builtin_amdgcn_mfma_f32_16x16x32_bf16(af, b1, sc1, 0, 0, 0);
        }
        __syncthreads();   // ALL waves' kbuf reads done before P-writes clobber kbuf region

        // ---------------- online softmax (base-2, scale folded) ----------------
        float alpha[4];
        #pragma unroll
        for (int r = 0; r < 4; ++r) {
            float mx = fmaxf(sc0[r], sc1[r]);
            mx = fmaxf(mx, __shfl_xor(mx, 1));
            mx = fmaxf(mx, __shfl_xor(mx, 2));
            mx = fmaxf(mx, __shfl_xor(mx, 4));
            mx = fmaxf(mx, __shfl_xor(mx, 8));
            const float mn = fmaxf(m2[r], mx * CL2);
            const float al = exp2f(m2[r] - mn);
            const float p0 = exp2f(fmaf(sc0[r], CL2, -mn));
            const float p1 = exp2f(fmaf(sc1[r], CL2, -mn));
            float sm = p0 + p1;
            sm += __shfl_xor(sm, 1);
            sm += __shfl_xor(sm, 2);
            sm += __shfl_xor(sm, 4);
            sm += __shfl_xor(sm, 8);
            lsum[r] = al * lsum[r] + sm;
            m2[r] = mn;
            alpha[r] = al;
            prow[(lq * 4 + r) * PROW + l16]      = bf1(p0);
            prow[(lq * 4 + r) * PROW + 16 + l16] = bf1(p1);
        }
        #pragma unroll
        for (int nf = 0; nf < 32; ++nf) {
            acc[nf][0] *= alpha[0];
            acc[nf][1] *= alpha[1];
            acc[nf][2] *= alpha[2];
            acc[nf][3] *= alpha[3];
        }
        // P writes are wave-locally consumed: drain LDS, pin order
        asm volatile("s_waitcnt lgkmcnt(0)" ::: "memory");
        __builtin_amdgcn_sched_barrier(0);

        // ---------------- PV : acc[16h x 512d] += P[16x32] * V[32x512] ----------------
        const s16x8 pf = *(const s16x8*)&prow[l16 * PROW + lq * 8];
        #pragma unroll
        for (int nf = 0; nf < 32; ++nf) {
            const int ro = (nf * 16 + l16) * VT_ROW + lq * 8;
            union { s16x4 h[2]; s16x8 v; } uu;
            uu.h[0] = *(const s16x4*)&vbuf[ro];
            uu.h[1] = *(const s16x4*)&vbuf[ro + 4];
            acc[nf] = __builtin_amdgcn_mfma_f32_16x16x32_bf16(pf, uu.v, acc[nf], 0, 0, 0);
        }
        __syncthreads();   // PV reads (vbuf + pbuf-in-kbuf) done before next staging
    }

    // ---------------- write partials (unnormalized O bf16, + m,l) ----------------
    const size_t obase = (size_t)(b * NCHUNK + chunk) * NH_ * ND_;
    #pragma unroll
    for (int nf = 0; nf < 32; ++nf) {
        #pragma unroll
        for (int r = 0; r < 4; ++r) {
            const int h = hgrp * 64 + wv * 16 + lq * 4 + r;
            const int d = nf * 16 + l16;
            opart[obase + (size_t)h * ND_ + d] = bf1(acc[nf][r]);
        }
    }
    if (l16 == 0) {
        #pragma unroll
        for (int r = 0; r < 4; ++r) {
            const int h = hgrp * 64 + wv * 16 + lq * 4 + r;
            const int idx = (b * NCHUNK + chunk) * NH_ + h;
            mlbuf[2 * idx]     = m2[r];
            mlbuf[2 * idx + 1] = lsum[r];
        }
    }
}

__global__ __launch_bounds__(128) void mla_combine(
    const unsigned short* __restrict__ opart, const float* __restrict__ mlbuf,
    float* __restrict__ out)
{
    const int bh = blockIdx.x;
    const int b = bh >> 7, h = bh & 127;
    const int tid = threadIdx.x;

    float mv[NCHUNK], lv[NCHUNK];
    float m = -1e30f;
    #pragma unroll
    for (int c = 0; c < NCHUNK; ++c) {
        const int idx = (b * NCHUNK + c) * NH_ + h;
        mv[c] = mlbuf[2 * idx];
        lv[c] = mlbuf[2 * idx + 1];
        m = fmaxf(m, mv[c]);
    }
    float L = 0.f, w[NCHUNK];
    #pragma unroll
    for (int c = 0; c < NCHUNK; ++c) { w[c] = exp2f(mv[c] - m); L += w[c] * lv[c]; }
    const float inv = 1.0f / L;

    const int d0 = tid * 4;
    float a0 = 0.f, a1 = 0.f, a2 = 0.f, a3 = 0.f;
    #pragma unroll
    for (int c = 0; c < NCHUNK; ++c) {
        const unsigned short* p = opart + (((size_t)(b * NCHUNK + c) * NH_ + h) * ND_ + d0);
        const unsigned u0 = *(const unsigned*)(p);
        const unsigned u1 = *(const unsigned*)(p + 2);
        a0 += w[c] * __uint_as_float((u0 & 0xffffu) << 16);
        a1 += w[c] * __uint_as_float(u0 & 0xffff0000u);
        a2 += w[c] * __uint_as_float((u1 & 0xffffu) << 16);
        a3 += w[c] * __uint_as_float(u1 & 0xffff0000u);
    }
    f32x4 res;
    res.x = a0 * inv; res.y = a1 * inv; res.z = a2 * inv; res.w = a3 * inv;
    *(f32x4*)(out + ((size_t)(b * NH_ + h) * ND_ + d0)) = res;
}

extern "C" void kernel_launch(void* const* d_in, const int* in_sizes, int n_in,
                              void* d_out, int out_size, void* d_ws, size_t ws_size,
                              hipStream_t stream) {
    const float* q    = (const float*)d_in[0];
    const float* q_pe = (const float*)d_in[1];
    const float* k    = (const float*)d_in[2];
    const float* k_pe = (const float*)d_in[3];

    unsigned short* opart = (unsigned short*)d_ws;
    float* mlbuf = (float*)((char*)d_ws + (size_t)NB_ * NCHUNK * NH_ * ND_ * sizeof(unsigned short));
    unsigned short* qbf = (unsigned short*)((char*)mlbuf + (size_t)NB_ * NCHUNK * NH_ * 2 * sizeof(float));

    const int qpairs = NB_ * NH_ * (NDT_ / 2);
    qcvt<<<(qpairs + 255) / 256, 256, 0, stream>>>(q, q_pe, qbf);
    mla_attn<<<512, NT_, SMEM_BYTES, stream>>>(k, k_pe, qbf, opart, mlbuf);
    mla_combine<<<NB_ * NH_, 128, 0, stream>>>(opart, mlbuf, (float*)d_out);
}

// Round 9
// 108.775 us; speedup vs baseline: 2.0250x; 2.0250x over previous
//
#include <hip/hip_runtime.h>
#include <hip/hip_bf16.h>

typedef __attribute__((ext_vector_type(4))) float  f32x4;
typedef __attribute__((ext_vector_type(8))) short  s16x8;
typedef __attribute__((ext_vector_type(4))) short  s16x4;

#define NB_    16
#define NH_    128
#define NS_    4096
#define ND_    512
#define NDPE_  64
#define NDT_   576
#define NCHUNK 16
#define CHUNK_ 256
#define TS_    32
#define NSUB_  8
#define NT_    512

#define KROW_S 584   // kbuf row: 576 + 8 pad shorts (writes 2-way, b128 reads min-uniform)
#define VT_ROW 36    // vbufT row: 32 + 4 pad shorts (72 B rows; b64 writes/reads aligned, ~min-uniform banks)
#define PROW   40    // pbuf row

#define KBUF_BYTES (TS_ * KROW_S * 2)              // 37376
#define VBUF_OFF   KBUF_BYTES
#define VBUF_BYTES (ND_ * VT_ROW * 2)              // 36864
#define PBUF_OFF   (VBUF_OFF + VBUF_BYTES)         // 74240
#define SMEM_BYTES (PBUF_OFF + 8 * 16 * PROW * 2)  // 84480

// (1/sqrt(576)) * log2(e)
#define CL2 0.06011229337037348f

__device__ __forceinline__ unsigned pk_bf16(float a, float b) {
    union { __hip_bfloat162 h2; unsigned u; } c;
    c.h2 = __float22bfloat162_rn(make_float2(a, b));
    return c.u;
}
__device__ __forceinline__ unsigned short bf1(float a) {
    union { __hip_bfloat16 h; unsigned short u; } c;
    c.h = __float2bfloat16(a);
    return c.u;
}

__global__ void qcvt(const float* __restrict__ q, const float* __restrict__ q_pe,
                     unsigned short* __restrict__ qbf) {
    const int idx = blockIdx.x * 256 + threadIdx.x;   // bf16-pair index
    if (idx >= NB_ * NH_ * (NDT_ / 2)) return;
    const int bh = idx / (NDT_ / 2), pc = idx - bh * (NDT_ / 2);
    const int c = pc * 2;
    const float* src = (c < ND_) ? (q + (size_t)bh * ND_ + c)
                                 : (q_pe + (size_t)bh * NDPE_ + (c - ND_));
    *(unsigned*)&qbf[(size_t)bh * NDT_ + c] = pk_bf16(src[0], src[1]);
}

__global__ __launch_bounds__(NT_, 1) void mla_attn(
    const float* __restrict__ k, const float* __restrict__ k_pe,
    const unsigned short* __restrict__ qbf,
    unsigned short* __restrict__ opart, float* __restrict__ mlbuf)
{
    extern __shared__ char smem[];
    unsigned short* kbuf = (unsigned short*)(smem);              // [32][584] bf16 row-major K
    unsigned short* vbuf = (unsigned short*)(smem + VBUF_OFF);   // [512][36] bf16 V^T
    unsigned short* pbuf = (unsigned short*)(smem + PBUF_OFF);   // 8 waves x [16][40]

    const int chunk = blockIdx.x, b = blockIdx.y;
    const int tid = threadIdx.x;
    const int wv  = tid >> 6;
    const int l   = tid & 63;
    const int l16 = l & 15;
    const int lq  = l >> 4;

    f32x4 acc[32];
    #pragma unroll
    for (int i = 0; i < 32; ++i) acc[i] = (f32x4)0.0f;
    float m2[4]   = {-1e30f, -1e30f, -1e30f, -1e30f};
    float lsum[4] = {0.f, 0.f, 0.f, 0.f};

    const int sl   = tid >> 4;   // staging row 0..31 (= 4*wv + lq)
    const int ln16 = tid & 15;   // staging d-granule
    const int wb   = sl & ~3;    // 4*wv: this wave's 4-row s-base

    const unsigned short* qrowb =
        qbf + (size_t)(b * NH_ + wv * 16 + l16) * NDT_ + lq * 8;
    unsigned short* prow = pbuf + wv * 16 * PROW;

    for (int t = 0; t < NSUB_; ++t) {
        // ---------------- stage K sub-tile: f32 -> bf16, shfl-transposed V^T ----------------
        {
            const int sg = chunk * CHUNK_ + t * TS_ + sl;
            const float* krow   = k    + (size_t)(b * NS_ + sg) * ND_;
            const float* kperow = k_pe + (size_t)(b * NS_ + sg) * NDPE_;
            #pragma unroll
            for (int i = 0; i < 9; ++i) {
                const int d0 = ln16 * 4 + i * 64;
                f32x4 v;
                if (i < 8) v = *(const f32x4*)(krow + d0);
                else       v = *(const f32x4*)(kperow + (d0 - ND_));
                const unsigned x0 = pk_bf16(v.x, v.y);   // {d0, d0+1} at row sl
                const unsigned x1 = pk_bf16(v.z, v.w);   // {d0+2, d0+3}
                *(unsigned long long*)&kbuf[sl * KROW_S + d0] =
                    (unsigned long long)x0 | ((unsigned long long)x1 << 32);
                if (i < 8) {
                    // 4x4 (s x d) transpose across the 4 lane-quarters (rows sl = wb..wb+3)
                    const unsigned t0 = __shfl_xor(x0, 16);
                    const unsigned t1 = __shfl_xor(x1, 16);
                    unsigned y0, y1, y2, y3;
                    if ((lq & 1) == 0) {
                        y0 = (t0 << 16) | (x0 & 0xffffu);
                        y1 = (t0 & 0xffff0000u) | (x0 >> 16);
                        y2 = (t1 << 16) | (x1 & 0xffffu);
                        y3 = (t1 & 0xffff0000u) | (x1 >> 16);
                    } else {
                        y0 = (x0 << 16) | (t0 & 0xffffu);
                        y1 = (x0 & 0xffff0000u) | (t0 >> 16);
                        y2 = (x1 << 16) | (t1 & 0xffffu);
                        y3 = (x1 & 0xffff0000u) | (t1 >> 16);
                    }
                    // y_j = column (d0+j) restricted to row-pair (2*(lq>>1), +1)
                    const unsigned k01 = (lq & 1) ? y1 : y0;
                    const unsigned k23 = (lq & 1) ? y3 : y2;
                    const unsigned keep = (lq & 2) ? k23 : k01;   // y[lq]
                    const unsigned send = (lq & 2) ? k01 : k23;   // y[lq^2]
                    const unsigned recv = __shfl_xor(send, 32);
                    const unsigned tlo = (lq & 2) ? recv : keep;  // rows wb+0,1 of col d0+lq
                    const unsigned thi = (lq & 2) ? keep : recv;  // rows wb+2,3
                    *(unsigned long long*)&vbuf[(d0 + lq) * VT_ROW + wb] =
                        (unsigned long long)tlo | ((unsigned long long)thi << 32);
                }
            }
        }
        __syncthreads();

        // ---------------- QK^T : scores[16h x 32s] per wave ----------------
        const unsigned short* qp = qrowb;
        asm volatile("" : "+v"(qp));    // block cross-tile hoist of Q frags (anti-spill)
        f32x4 sc0 = (f32x4)0.0f, sc1 = (f32x4)0.0f;
        #pragma unroll
        for (int kk = 0; kk < 18; ++kk) {
            const int d0 = kk * 32 + lq * 8;
            const s16x8 af   = *(const s16x8*)(qp + kk * 32);
            const s16x8 bf0  = *(const s16x8*)&kbuf[(l16     ) * KROW_S + d0];
            const s16x8 bf1v = *(const s16x8*)&kbuf[(l16 + 16) * KROW_S + d0];
            sc0 = __builtin_amdgcn_mfma_f32_16x16x32_bf16(af, bf0,  sc0, 0, 0, 0);
            sc1 = __builtin_amdgcn_mfma_f32_16x16x32_bf16(af, bf1v, sc1, 0, 0, 0);
        }

        // ---------------- online softmax (base-2, scale folded) ----------------
        float alpha[4];
        #pragma unroll
        for (int r = 0; r < 4; ++r) {
            float mx = fmaxf(sc0[r], sc1[r]);
            mx = fmaxf(mx, __shfl_xor(mx, 1));
            mx = fmaxf(mx, __shfl_xor(mx, 2));
            mx = fmaxf(mx, __shfl_xor(mx, 4));
            mx = fmaxf(mx, __shfl_xor(mx, 8));
            const float mn = fmaxf(m2[r], mx * CL2);
            const float al = exp2f(m2[r] - mn);
            const float p0 = exp2f(fmaf(sc0[r], CL2, -mn));
            const float p1 = exp2f(fmaf(sc1[r], CL2, -mn));
            float sm = p0 + p1;
            sm += __shfl_xor(sm, 1);
            sm += __shfl_xor(sm, 2);
            sm += __shfl_xor(sm, 4);
            sm += __shfl_xor(sm, 8);
            lsum[r] = al * lsum[r] + sm;
            m2[r] = mn;
            alpha[r] = al;
            prow[(lq * 4 + r) * PROW + l16]      = bf1(p0);
            prow[(lq * 4 + r) * PROW + 16 + l16] = bf1(p1);
        }
        #pragma unroll
        for (int nf = 0; nf < 32; ++nf) {
            acc[nf][0] *= alpha[0];
            acc[nf][1] *= alpha[1];
            acc[nf][2] *= alpha[2];
            acc[nf][3] *= alpha[3];
        }
        // P writes are wave-locally consumed: drain LDS, pin order
        asm volatile("s_waitcnt lgkmcnt(0)" ::: "memory");
        __builtin_amdgcn_sched_barrier(0);

        // ---------------- PV : acc[16h x 512d] += P[16x32] * V[32x512] ----------------
        const s16x8 pf = *(const s16x8*)&prow[l16 * PROW + lq * 8];
        #pragma unroll
        for (int nf = 0; nf < 32; ++nf) {
            const int ro = (nf * 16 + l16) * VT_ROW + lq * 8;
            union { s16x4 h[2]; s16x8 v; } u;
            u.h[0] = *(const s16x4*)&vbuf[ro];
            u.h[1] = *(const s16x4*)&vbuf[ro + 4];
            acc[nf] = __builtin_amdgcn_mfma_f32_16x16x32_bf16(pf, u.v, acc[nf], 0, 0, 0);
        }
        __syncthreads();   // all LDS reads done before next tile's staging writes
    }

    // ---------------- write partials (unnormalized O bf16, + m,l) ----------------
    const size_t obase = (size_t)(b * NCHUNK + chunk) * NH_ * ND_;
    #pragma unroll
    for (int nf = 0; nf < 32; ++nf) {
        #pragma unroll
        for (int r = 0; r < 4; ++r) {
            const int h = wv * 16 + lq * 4 + r;
            const int d = nf * 16 + l16;
            opart[obase + (size_t)h * ND_ + d] = bf1(acc[nf][r]);
        }
    }
    if (l16 == 0) {
        #pragma unroll
        for (int r = 0; r < 4; ++r) {
            const int h = wv * 16 + lq * 4 + r;
            const int idx = (b * NCHUNK + chunk) * NH_ + h;
            mlbuf[2 * idx]     = m2[r];
            mlbuf[2 * idx + 1] = lsum[r];
        }
    }
}

__global__ __launch_bounds__(128) void mla_combine(
    const unsigned short* __restrict__ opart, const float* __restrict__ mlbuf,
    float* __restrict__ out)
{
    const int bh = blockIdx.x;
    const int b = bh >> 7, h = bh & 127;
    const int tid = threadIdx.x;

    float mv[NCHUNK], lv[NCHUNK];
    float m = -1e30f;
    #pragma unroll
    for (int c = 0; c < NCHUNK; ++c) {
        const int idx = (b * NCHUNK + c) * NH_ + h;
        mv[c] = mlbuf[2 * idx];
        lv[c] = mlbuf[2 * idx + 1];
        m = fmaxf(m, mv[c]);
    }
    float L = 0.f, w[NCHUNK];
    #pragma unroll
    for (int c = 0; c < NCHUNK; ++c) { w[c] = exp2f(mv[c] - m); L += w[c] * lv[c]; }
    const float inv = 1.0f / L;

    const int d0 = tid * 4;
    float a0 = 0.f, a1 = 0.f, a2 = 0.f, a3 = 0.f;
    #pragma unroll
    for (int c = 0; c < NCHUNK; ++c) {
        const unsigned short* p = opart + (((size_t)(b * NCHUNK + c) * NH_ + h) * ND_ + d0);
        const unsigned u0 = *(const unsigned*)(p);
        const unsigned u1 = *(const unsigned*)(p + 2);
        a0 += w[c] * __uint_as_float((u0 & 0xffffu) << 16);
        a1 += w[c] * __uint_as_float(u0 & 0xffff0000u);
        a2 += w[c] * __uint_as_float((u1 & 0xffffu) << 16);
        a3 += w[c] * __uint_as_float(u1 & 0xffff0000u);
    }
    f32x4 res;
    res.x = a0 * inv; res.y = a1 * inv; res.z = a2 * inv; res.w = a3 * inv;
    *(f32x4*)(out + ((size_t)(b * NH_ + h) * ND_ + d0)) = res;
}

extern "C" void kernel_launch(void* const* d_in, const int* in_sizes, int n_in,
                              void* d_out, int out_size, void* d_ws, size_t ws_size,
                              hipStream_t stream) {
    const float* q    = (const float*)d_in[0];
    const float* q_pe = (const float*)d_in[1];
    const float* k    = (const float*)d_in[2];
    const float* k_pe = (const float*)d_in[3];

    unsigned short* opart = (unsigned short*)d_ws;
    float* mlbuf = (float*)((char*)d_ws + (size_t)NB_ * NCHUNK * NH_ * ND_ * sizeof(unsigned short));
    unsigned short* qbf = (unsigned short*)((char*)mlbuf + (size_t)NB_ * NCHUNK * NH_ * 2 * sizeof(float));

    const int qpairs = NB_ * NH_ * (NDT_ / 2);
    qcvt<<<(qpairs + 255) / 256, 256, 0, stream>>>(q, q_pe, qbf);
    mla_attn<<<dim3(NCHUNK, NB_), NT_, SMEM_BYTES, stream>>>(k, k_pe, qbf, opart, mlbuf);
    mla_combine<<<NB_ * NH_, 128, 0, stream>>>(opart, mlbuf, (float*)d_out);
}